// Round 8
// baseline (2168.686 us; speedup 1.0000x reference)
//
#include <hip/hip_runtime.h>

typedef __attribute__((ext_vector_type(8))) short s16x8;
typedef __attribute__((ext_vector_type(4))) short s16x4;
typedef __attribute__((ext_vector_type(4))) float f32x4;

__device__ __forceinline__ unsigned short f2bf(float f){
    union{float f;unsigned u;}v; v.f=f;
    unsigned u=v.u;
    unsigned r=(u+0x7fffu+((u>>16)&1u))>>16;
    return (unsigned short)r;
}
__device__ __forceinline__ float bf2f(unsigned short s){
    union{unsigned u;float f;}v; v.u=((unsigned)s)<<16; return v.f;
}
__device__ __forceinline__ unsigned pk2t(float a, float b){
    return (__float_as_uint(a)>>16) | (__float_as_uint(b) & 0xffff0000u);
}
__device__ __forceinline__ unsigned pk2r(float a, float b){
    return (unsigned)f2bf(a) | ((unsigned)f2bf(b)<<16);
}
__device__ __forceinline__ f32x4 fmax4(f32x4 a, f32x4 b){
    f32x4 r; r[0]=fmaxf(a[0],b[0]); r[1]=fmaxf(a[1],b[1]);
    r[2]=fmaxf(a[2],b[2]); r[3]=fmaxf(a[3],b[3]); return r;
}

__device__ __forceinline__ void gl16(const void* g, void* l){
    __builtin_amdgcn_global_load_lds(
        (const __attribute__((address_space(1))) void*)g,
        (__attribute__((address_space(3))) void*)l, 16, 0, 0);
}

#define ATT_SCALE 0.125f

// ===========================================================================
// Flash attention (unchanged).
// ===========================================================================
__global__ __launch_bounds__(256) void flash_k(
    const unsigned short* __restrict__ qkv,
    const unsigned short* __restrict__ vt,
    unsigned short* __restrict__ o)
{
    __shared__ __align__(16) unsigned short Pl[4][2048];
    const int t=threadIdx.x, w=t>>6, lane=t&63;
    const int lr=lane&15, lg=lane>>4;
    const int zb=blockIdx.y>>4, zh=blockIdx.y&15;
    const long sr0 = (long)zb*2048 + blockIdx.x*128 + w*32;
    const unsigned short* qb    = qkv + sr0*3072 + zh*64;
    const unsigned short* kbase = qkv + ((long)zb*2048)*3072 + 1024 + zh*64;
    const unsigned short* vtb   = vt + (long)zb*2097152 + (long)zh*131072;

    s16x8 qf[2][2];
    #pragma unroll
    for(int qg=0;qg<2;qg++)
        #pragma unroll
        for(int kc=0;kc<2;kc++)
            qf[qg][kc] = *(const s16x8*)(qb + (qg*16+lr)*3072 + kc*32 + lg*8);

    float m0=-1e30f, m1=-1e30f, l0=0.f, l1=0.f;
    f32x4 oa[2][4];
    #pragma unroll
    for(int qg=0;qg<2;qg++)
        #pragma unroll
        for(int dt=0;dt<4;dt++) oa[qg][dt]=f32x4{0.f,0.f,0.f,0.f};

    char* Pw = (char*)&Pl[w][0];
    const int swz = (lr&7)<<4;

    for(int kv0=0; kv0<2048; kv0+=64){
        f32x4 s[2][4];
        __builtin_amdgcn_s_setprio(1);
        #pragma unroll
        for(int kb=0;kb<4;kb++){
            const unsigned short* kr = kbase + (long)(kv0+kb*16+lr)*3072;
            s16x8 a0 = *(const s16x8*)(kr + lg*8);
            s16x8 a1 = *(const s16x8*)(kr + 32 + lg*8);
            #pragma unroll
            for(int qg=0;qg<2;qg++){
                f32x4 z4{0.f,0.f,0.f,0.f};
                z4 = __builtin_amdgcn_mfma_f32_16x16x32_bf16(a0, qf[qg][0], z4,0,0,0);
                s[qg][kb] = __builtin_amdgcn_mfma_f32_16x16x32_bf16(a1, qf[qg][1], z4,0,0,0);
            }
        }
        __builtin_amdgcn_s_setprio(0);
        s16x8 vreg[4][2];
        #pragma unroll
        for(int dt=0;dt<4;dt++){
            const unsigned short* vr = vtb + (dt*16+lr)*2048 + kv0;
            vreg[dt][0] = *(const s16x8*)(vr + lg*8);
            vreg[dt][1] = *(const s16x8*)(vr + 32 + lg*8);
        }
        #pragma unroll
        for(int qg=0;qg<2;qg++){
            float& m = qg? m1:m0;
            float& l = qg? l1:l0;
            f32x4 mx4 = fmax4(fmax4(s[qg][0],s[qg][1]),fmax4(s[qg][2],s[qg][3]));
            float bm = fmaxf(fmaxf(mx4[0],mx4[1]),fmaxf(mx4[2],mx4[3]));
            bm = fmaxf(bm, __shfl_xor(bm,16));
            bm = fmaxf(bm, __shfl_xor(bm,32));
            const float mn = fmaxf(m, bm);
            const float sc = __expf((m-mn)*ATT_SCALE);
            m = mn;
            float rs=0.f;
            #pragma unroll
            for(int kb=0;kb<4;kb++){
                f32x4 p;
                #pragma unroll
                for(int r=0;r<4;r++){ p[r]=__expf((s[qg][kb][r]-mn)*ATT_SCALE); rs+=p[r]; }
                s[qg][kb]=p;
            }
            rs += __shfl_xor(rs,16);
            rs += __shfl_xor(rs,32);
            l = l*sc + rs;
            #pragma unroll
            for(int dt=0;dt<4;dt++) oa[qg][dt] = oa[qg][dt]*sc;
            #pragma unroll
            for(int kb=0;kb<4;kb++){
                uint2 pw;
                pw.x = pk2t(s[qg][kb][0], s[qg][kb][1]);
                pw.y = pk2t(s[qg][kb][2], s[qg][kb][3]);
                *(uint2*)(Pw + (qg*16+lr)*128 + ((kb*32+lg*8)^swz)) = pw;
            }
        }
        asm volatile("s_waitcnt lgkmcnt(0)" ::: "memory");
        s16x8 pb0[2], pb1[2];
        #pragma unroll
        for(int qg=0;qg<2;qg++){
            pb0[qg] = *(const s16x8*)(Pw + (qg*16+lr)*128 + ((     lg*16)^swz));
            pb1[qg] = *(const s16x8*)(Pw + (qg*16+lr)*128 + ((64 + lg*16)^swz));
        }
        __builtin_amdgcn_s_setprio(1);
        #pragma unroll
        for(int dt=0;dt<4;dt++){
            #pragma unroll
            for(int qg=0;qg<2;qg++){
                oa[qg][dt] = __builtin_amdgcn_mfma_f32_16x16x32_bf16(vreg[dt][0], pb0[qg], oa[qg][dt],0,0,0);
                oa[qg][dt] = __builtin_amdgcn_mfma_f32_16x16x32_bf16(vreg[dt][1], pb1[qg], oa[qg][dt],0,0,0);
            }
        }
        __builtin_amdgcn_s_setprio(0);
    }
    #pragma unroll
    for(int qg=0;qg<2;qg++){
        const float inv = 1.f/(qg? l1:l0);
        #pragma unroll
        for(int dt=0;dt<4;dt++){
            uint2 st;
            st.x = pk2r(oa[qg][dt][0]*inv, oa[qg][dt][1]*inv);
            st.y = pk2r(oa[qg][dt][2]*inv, oa[qg][dt][3]*inv);
            *(uint2*)(o + (sr0+qg*16+lr)*1024 + zh*64 + dt*16 + lg*4) = st;
        }
    }
}

// ===========================================================================
// 4-barrier 256x256 GEMM (bf16/GEGLU epilogues) — used for FF1.
// ===========================================================================
template<bool OBF16,bool BIAS,bool GEGLU>
__global__ __launch_bounds__(512,2) void gemm8_k(
    const unsigned short* __restrict__ A,
    const unsigned short* __restrict__ B,
    const float* __restrict__ bias,
    void* __restrict__ Cp,
    int K,int lda,int ldb,int ldc)
{
    __shared__ __align__(16) char lds[131072];
    const int t=threadIdx.x, w=t>>6, lane=t&63;
    const int wr=w>>2, wc=w&3;
    const int lr=lane&15, lg=lane>>4;

    const int nwg = gridDim.x*gridDim.y;
    const int id  = blockIdx.y*gridDim.x + blockIdx.x;
    const int nid = (id&7)*(nwg>>3) + (id>>3);
    const long row0 = (long)(nid % gridDim.x)*256;
    const long col0 = (long)(nid / gridDim.x)*256;

    const int NT = K>>6;

    const int csw0 = (lg*16) ^ ((lr&7)<<4);
    const int aRow = (wr*64+lr)*128;
    const int bRow = (wc*32+lr)*128;

    const int sro = t>>3;
    const int sce = (((t&7) ^ ((t>>3)&7))<<3);

#define STAGE(gp, ld_, lb) do{ \
    const unsigned short* _g=(gp); char* _l=(lb); \
    gl16(_g + (long)sro*(ld_) + sce, _l + t*16); \
    gl16(_g + (long)(sro+64)*(ld_) + sce, _l + 8192 + t*16); }while(0)

#define LDA8(m,kk) (*(const s16x8*)(Ab_ + aRow + ((m)&3)*2048 + ((m)>>2)*16384 + ((kk)? (csw0^64):csw0)))
#define LDB8(n,kk) (*(const s16x8*)(Bb_ + bRow + ((n)&1)*2048 + ((n)>>1)*16384 + ((kk)? (csw0^64):csw0)))

    f32x4 acc[8][4];
    #pragma unroll
    for(int m=0;m<8;m++)
        #pragma unroll
        for(int n=0;n<4;n++) acc[m][n]=f32x4{0.f,0.f,0.f,0.f};

    STAGE(A + row0*lda,        lda, lds);
    STAGE(B + col0*ldb,        ldb, lds+65536);
    STAGE(A + (row0+128)*lda,  lda, lds+16384);
    STAGE(B + (col0+128)*ldb,  ldb, lds+65536+16384);
    STAGE(A + row0*lda + 64,   lda, lds+32768);
    STAGE(B + col0*ldb + 64,   ldb, lds+65536+32768);
    asm volatile("s_waitcnt vmcnt(4)" ::: "memory");
    __builtin_amdgcn_s_barrier();

    for(int tt=0; tt<NT; ++tt){
        char* Ab_ = lds + ((tt&1)<<15);
        char* Bb_ = lds + 65536 + ((tt&1)<<15);
        char* An  = lds + (((tt+1)&1)<<15);
        char* Bn  = lds + 65536 + (((tt+1)&1)<<15);
        const int k1=(tt+1)<<6, k2=(tt+2)<<6;
        s16x8 a[4][2], b[4][2];

        #pragma unroll
        for(int m=0;m<4;m++){ a[m][0]=LDA8(m,0); a[m][1]=LDA8(m,1); }
        #pragma unroll
        for(int n=0;n<4;n++){ b[n][0]=LDB8(n,0); b[n][1]=LDB8(n,1); }
        if(tt+1<NT){
            STAGE(A + (row0+128)*lda + k1, lda, An+16384);
            STAGE(B + (col0+128)*ldb + k1, ldb, Bn+16384);
        }
        __builtin_amdgcn_s_barrier();
        __builtin_amdgcn_s_setprio(1);
        #pragma unroll
        for(int kk=0;kk<2;kk++)
            #pragma unroll
            for(int m=0;m<4;m++)
                #pragma unroll
                for(int n=0;n<4;n++)
                    acc[m][n]=__builtin_amdgcn_mfma_f32_16x16x32_bf16(a[m][kk],b[n][kk],acc[m][n],0,0,0);
        __builtin_amdgcn_s_setprio(0);
        __builtin_amdgcn_s_barrier();

        #pragma unroll
        for(int m=0;m<4;m++){ a[m][0]=LDA8(m+4,0); a[m][1]=LDA8(m+4,1); }
        if(tt+2<NT){
            STAGE(A + row0*lda + k2, lda, Ab_);
            STAGE(B + col0*ldb + k2, ldb, Bb_);
        }
        __builtin_amdgcn_s_barrier();
        __builtin_amdgcn_s_setprio(1);
        #pragma unroll
        for(int kk=0;kk<2;kk++)
            #pragma unroll
            for(int m=0;m<4;m++)
                #pragma unroll
                for(int n=0;n<4;n++)
                    acc[m+4][n]=__builtin_amdgcn_mfma_f32_16x16x32_bf16(a[m][kk],b[n][kk],acc[m+4][n],0,0,0);
        __builtin_amdgcn_s_setprio(0);
        if(tt+2<NT) asm volatile("s_waitcnt vmcnt(4)" ::: "memory");
        else        asm volatile("s_waitcnt vmcnt(0)" ::: "memory");
        __builtin_amdgcn_s_barrier();
    }

    if constexpr(GEGLU){
        const long hc0 = col0>>1;
        #pragma unroll
        for(int m=0;m<8;m++){
            #pragma unroll
            for(int n=0;n<2;n++){
                #pragma unroll
                for(int rr=0;rr<4;rr++){
                    const long grow = row0 + wr*64 + (m&3)*16 + (m>>2)*128 + lg*4 + rr;
                    const long g    = hc0 + wc*32 + n*16 + lr;
                    float gg = acc[m][n][rr]   + bias[g];
                    float vl = acc[m][n+2][rr] + bias[4096+g];
                    float ge = 0.5f*gg*(1.f+erff(gg*0.70710678118654752f));
                    ((unsigned short*)Cp)[grow*(long)ldc + g] = f2bf(ge*vl);
                }
            }
        }
    } else {
        #pragma unroll
        for(int m=0;m<8;m++){
            #pragma unroll
            for(int n=0;n<4;n++){
                #pragma unroll
                for(int rr=0;rr<4;rr++){
                    const long grow = row0 + wr*64 + (m&3)*16 + (m>>2)*128 + lg*4 + rr;
                    const long gcol = col0 + wc*32 + (n&1)*16 + (n>>1)*128 + lr;
                    float vv = acc[m][n][rr];
                    if constexpr(BIAS) vv += bias[gcol];
                    if constexpr(OBF16) ((unsigned short*)Cp)[grow*(long)ldc+gcol]=f2bf(vv);
                    else                ((float*)Cp)[grow*(long)ldc+gcol]=vv;
                }
            }
        }
    }
#undef STAGE
#undef LDA8
#undef LDB8
}

// ===========================================================================
// Persistent logits GEMM: 256 blocks; each owns one 256-row panel (A L2-hot)
// and loops over ~8 col-panels of 256. f32 out, bias, swizzled LDS epilogue
// with nontemporal stores.
// ===========================================================================
__global__ __launch_bounds__(512,2) void gemm8p_k(
    const unsigned short* __restrict__ A,
    const unsigned short* __restrict__ B,
    const float* __restrict__ bias,
    float* __restrict__ Cp,
    int K,int lda,int ldb,int ldc)
{
    __shared__ __align__(16) char lds[131072];
    const int t=threadIdx.x, w=t>>6, lane=t&63;
    const int wr=w>>2, wc=w&3;
    const int lr=lane&15, lg=lane>>4;

    const int id  = blockIdx.x;              // 256 blocks
    const int nid = (id&7)*32 + (id>>3);     // XCD-bijective
    const long row0 = (long)(nid & 15)*256;  // 16 row panels
    const int cg = nid>>4;                   // 16 col groups (siblings share XCD)
    const int ncols = (cg<13)? 8 : 7;        // 13*8 + 3*7 = 125
    const int c0 = cg*8 - ((cg>13)? (cg-13) : 0);

    const int NT = K>>6;
    const int csw0 = (lg*16) ^ ((lr&7)<<4);
    const int aRow = (wr*64+lr)*128;
    const int bRow = (wc*32+lr)*128;
    const int sro = t>>3;
    const int sce = (((t&7) ^ ((t>>3)&7))<<3);
    const int lc4 = (t&63)<<2;

#define STAGE(gp, ld_, lb) do{ \
    const unsigned short* _g=(gp); char* _l=(lb); \
    gl16(_g + (long)sro*(ld_) + sce, _l + t*16); \
    gl16(_g + (long)(sro+64)*(ld_) + sce, _l + 8192 + t*16); }while(0)

#define LDA8(m,kk) (*(const s16x8*)(Ab_ + aRow + ((m)&3)*2048 + ((m)>>2)*16384 + ((kk)? (csw0^64):csw0)))
#define LDB8(n,kk) (*(const s16x8*)(Bb_ + bRow + ((n)&1)*2048 + ((n)>>1)*16384 + ((kk)? (csw0^64):csw0)))

    for(int ci=0; ci<ncols; ci++){
        const long col0 = (long)(c0+ci)*256;

        f32x4 acc[8][4];
        #pragma unroll
        for(int m=0;m<8;m++)
            #pragma unroll
            for(int n=0;n<4;n++) acc[m][n]=f32x4{0.f,0.f,0.f,0.f};

        STAGE(A + row0*lda,        lda, lds);
        STAGE(B + col0*ldb,        ldb, lds+65536);
        STAGE(A + (row0+128)*lda,  lda, lds+16384);
        STAGE(B + (col0+128)*ldb,  ldb, lds+65536+16384);
        STAGE(A + row0*lda + 64,   lda, lds+32768);
        STAGE(B + col0*ldb + 64,   ldb, lds+65536+32768);
        asm volatile("s_waitcnt vmcnt(4)" ::: "memory");
        __builtin_amdgcn_s_barrier();

        for(int tt=0; tt<NT; ++tt){
            char* Ab_ = lds + ((tt&1)<<15);
            char* Bb_ = lds + 65536 + ((tt&1)<<15);
            char* An  = lds + (((tt+1)&1)<<15);
            char* Bn  = lds + 65536 + (((tt+1)&1)<<15);
            const int k1=(tt+1)<<6, k2=(tt+2)<<6;
            s16x8 a[4][2], b[4][2];

            #pragma unroll
            for(int m=0;m<4;m++){ a[m][0]=LDA8(m,0); a[m][1]=LDA8(m,1); }
            #pragma unroll
            for(int n=0;n<4;n++){ b[n][0]=LDB8(n,0); b[n][1]=LDB8(n,1); }
            if(tt+1<NT){
                STAGE(A + (row0+128)*lda + k1, lda, An+16384);
                STAGE(B + (col0+128)*ldb + k1, ldb, Bn+16384);
            }
            __builtin_amdgcn_s_barrier();
            __builtin_amdgcn_s_setprio(1);
            #pragma unroll
            for(int kk=0;kk<2;kk++)
                #pragma unroll
                for(int m=0;m<4;m++)
                    #pragma unroll
                    for(int n=0;n<4;n++)
                        acc[m][n]=__builtin_amdgcn_mfma_f32_16x16x32_bf16(a[m][kk],b[n][kk],acc[m][n],0,0,0);
            __builtin_amdgcn_s_setprio(0);
            __builtin_amdgcn_s_barrier();

            #pragma unroll
            for(int m=0;m<4;m++){ a[m][0]=LDA8(m+4,0); a[m][1]=LDA8(m+4,1); }
            if(tt+2<NT){
                STAGE(A + row0*lda + k2, lda, Ab_);
                STAGE(B + col0*ldb + k2, ldb, Bb_);
            }
            __builtin_amdgcn_s_barrier();
            __builtin_amdgcn_s_setprio(1);
            #pragma unroll
            for(int kk=0;kk<2;kk++)
                #pragma unroll
                for(int m=0;m<4;m++)
                    #pragma unroll
                    for(int n=0;n<4;n++)
                        acc[m+4][n]=__builtin_amdgcn_mfma_f32_16x16x32_bf16(a[m][kk],b[n][kk],acc[m+4][n],0,0,0);
            __builtin_amdgcn_s_setprio(0);
            if(tt+2<NT) asm volatile("s_waitcnt vmcnt(4)" ::: "memory");
            else        asm volatile("s_waitcnt vmcnt(0)" ::: "memory");
            __builtin_amdgcn_s_barrier();
        }

        // swizzled LDS-staged coalesced f32 epilogue, nontemporal stores
        {
            float* L = (float*)lds;
            f32x4 bv = *(const f32x4*)(bias + col0 + lc4);
            #pragma unroll
            for(int ch=0; ch<2; ch++){
                __builtin_amdgcn_s_barrier();
                #pragma unroll
                for(int mm=0;mm<4;mm++){
                    #pragma unroll
                    for(int n=0;n<4;n++){
                        #pragma unroll
                        for(int rr=0;rr<4;rr++){
                            const int lrow = wr*64 + mm*16 + lg*4 + rr;
                            const int lcol = wc*32 + (n&1)*16 + (n>>1)*128 + lr;
                            const int pc = ((((lcol>>2) ^ (lrow&7))<<2) | (lcol&3));
                            L[lrow*256 + pc] = acc[ch*4+mm][n][rr];
                        }
                    }
                }
                __builtin_amdgcn_s_barrier();
                #pragma unroll
                for(int p=0;p<16;p++){
                    const int lrow = p*8 + (t>>6);
                    const int pc4 = (((lc4>>2) ^ (lrow&7))<<2);
                    f32x4 v4 = *(const f32x4*)(L + lrow*256 + pc4);
                    v4[0]+=bv[0]; v4[1]+=bv[1]; v4[2]+=bv[2]; v4[3]+=bv[3];
                    __builtin_nontemporal_store(v4,
                        (f32x4*)(Cp + (row0 + ch*128 + lrow)*(long)ldc + col0 + lc4));
                }
            }
            __builtin_amdgcn_s_barrier();   // LDS reads done before next tile stages
        }
    }
#undef STAGE
#undef LDA8
#undef LDB8
}

// ---------------------------------------------------------------------------
__global__ __launch_bounds__(256) void cat3_k(const float* __restrict__ a,
    const float* __restrict__ b, const float* __restrict__ c,
    float* __restrict__ out)
{
    const int i = blockIdx.x*256+threadIdx.x;
    const int l = i/3072, cc = i%3072;
    float v = (cc<1024)? a[l*1024+cc] : (cc<2048)? b[l*1024+cc-1024] : c[l*1024+cc-2048];
    out[i]=v;
}

// ---------------------------------------------------------------------------
// Fast 2-phase GEMM (m97 structure), 128-tile family (unchanged).
// ---------------------------------------------------------------------------
template<int BM,int BN,int WN,bool BIAS,bool RES,bool OBF16,bool SCL,bool SWAP,bool GEGLU>
__global__ __launch_bounds__(256) void gemm_bt(
    const unsigned short* __restrict__ A,
    const unsigned short* __restrict__ B,
    const unsigned short* __restrict__ B2,
    const float* __restrict__ bias,
    const float* __restrict__ res,
    void* __restrict__ Cp,
    int K,int lda,int ldb,int ldc,
    long aSb,long aSh,long bSb,long bSh,long cSb,long cSh,int zH)
{
    constexpr int BK=64;
    constexpr int WM=4/WN, WTM=BM/WM, WTN=BN/WN;
    constexpr int FM=WTM/16, FN=WTN/16;
    constexpr int CA=BM/8, CB=BN/8;
    __shared__ __align__(16) unsigned short As[BM*BK];
    __shared__ __align__(16) unsigned short Bs[BN*BK*(GEGLU?2:1)];

    const int t=threadIdx.x, w=t>>6, lane=t&63;
    const int wr=w/WN, wc=w%WN;
    const int lr=lane&15, lg=lane>>4;
    const int z=blockIdx.z, zb=z/zH, zh=z%zH;
    const long row0 = SWAP ? (long)blockIdx.x*BM : (long)blockIdx.y*BM;
    const long col0 = SWAP ? (long)blockIdx.y*BN : (long)blockIdx.x*BN;

    const unsigned short* Ab = A + zb*aSb + zh*aSh;
    const unsigned short* Bb = B + zb*bSb + zh*bSh;

    const int lr8 = lane>>3;
    const int lc8 = (lane&7)<<3;

    f32x4 acc[FM][FN];
    f32x4 acc2[GEGLU?FM:1][GEGLU?FN:1];
    #pragma unroll
    for(int i=0;i<FM;i++)
        #pragma unroll
        for(int j=0;j<FN;j++){
            acc[i][j]=f32x4{0.f,0.f,0.f,0.f};
            if constexpr(GEGLU) acc2[i][j]=f32x4{0.f,0.f,0.f,0.f};
        }

    const int NT=K/BK;
    for(int kt=0;kt<NT;kt++){
        const int kb=kt*BK;
        #pragma unroll
        for(int cc=0;cc<CA/4;cc++){
            const int c=cc*4+w;
            gl16(Ab + (row0 + c*8 + lr8)*(long)lda + kb + lc8, (char*)As + c*1024);
        }
        #pragma unroll
        for(int cc=0;cc<CB/4;cc++){
            const int c=cc*4+w;
            gl16(Bb + (col0 + c*8 + lr8)*(long)ldb + kb + lc8, (char*)Bs + c*1024);
        }
        if constexpr(GEGLU){
            #pragma unroll
            for(int cc=0;cc<CB/4;cc++){
                const int c=cc*4+w;
                gl16(B2 + (col0 + c*8 + lr8)*(long)ldb + kb + lc8,
                     (char*)Bs + (CB + c)*1024);
            }
        }
        __syncthreads();
        const unsigned short* Arp = As + (wr*WTM+lr)*BK + lg*8;
        const unsigned short* Brp = Bs + (wc*WTN+lr)*BK + lg*8;
        #pragma unroll
        for(int kk=0;kk<2;kk++){
            s16x8 af[FM], bfv[FN], bf2[GEGLU?FN:1];
            #pragma unroll
            for(int i=0;i<FM;i++) af[i] = *(const s16x8*)(Arp + i*16*BK + kk*32);
            #pragma unroll
            for(int j=0;j<FN;j++) bfv[j]= *(const s16x8*)(Brp + j*16*BK + kk*32);
            if constexpr(GEGLU){
                #pragma unroll
                for(int j=0;j<FN;j++) bf2[j]=*(const s16x8*)(Brp + BN*BK + j*16*BK + kk*32);
            }
            #pragma unroll
            for(int i=0;i<FM;i++)
                #pragma unroll
                for(int j=0;j<FN;j++){
                    acc[i][j]=__builtin_amdgcn_mfma_f32_16x16x32_bf16(af[i],bfv[j],acc[i][j],0,0,0);
                    if constexpr(GEGLU)
                        acc2[i][j]=__builtin_amdgcn_mfma_f32_16x16x32_bf16(af[i],bf2[j],acc2[i][j],0,0,0);
                }
        }
        __syncthreads();
    }
    #pragma unroll
    for(int i=0;i<FM;i++){
        #pragma unroll
        for(int j=0;j<FN;j++){
            #pragma unroll
            for(int r=0;r<4;r++){
                const long grow = row0 + wr*WTM + i*16 + lg*4 + r;
                const long gcol = col0 + wc*WTN + j*16 + lr;
                if constexpr(GEGLU){
                    float g  = acc[i][j][r]  + bias[gcol];
                    float vl = acc2[i][j][r] + bias[gcol+4096];
                    float ge = 0.5f*g*(1.f+erff(g*0.70710678118654752f));
                    ((unsigned short*)Cp)[grow*ldc+gcol] = f2bf(ge*vl);
                } else {
                    float vv=acc[i][j][r];
                    if constexpr(SCL)  vv*=ATT_SCALE;
                    if constexpr(BIAS) vv+=bias[gcol];
                    if constexpr(RES)  vv+=res[grow*ldc+gcol];
                    const long cidx = zb*cSb + zh*cSh + grow*ldc + gcol;
                    if constexpr(OBF16) ((unsigned short*)Cp)[cidx]=f2bf(vv);
                    else                ((float*)Cp)[cidx]=vv;
                }
            }
        }
    }
}

// ---------------------------------------------------------------------------
// Tiled 64x64 transpose, 16B vectorized stores.
// ---------------------------------------------------------------------------
template<bool IN32, bool REMAP>
__global__ __launch_bounds__(256) void tr_k(const void* __restrict__ in,
    unsigned short* __restrict__ out, int ldin, int ldout,
    long inZb, long inZh, long outZb, long outZh, int zH)
{
    __shared__ unsigned short tl[64][66];
    const int t=threadIdx.x;
    const int z=blockIdx.z, zb=z/zH, zh=z%zH;
    const long ib=(long)blockIdx.x*64*ldin + (long)blockIdx.y*64 + zb*inZb + zh*inZh;
    long orow = (long)blockIdx.y*64;
    if constexpr(REMAP){
        orow = (orow < 4096) ? ((orow>>7)*256 + (orow&127))
                             : (((orow-4096)>>7)*256 + 128 + ((orow-4096)&127));
    }
    const long ob=orow*ldout + (long)blockIdx.x*64 + zb*outZb + zh*outZh;
    const int r0=t>>3, c8=(t&7)*8;
    #pragma unroll
    for(int p=0;p<2;p++){
        const int rr=r0+p*32;
        if constexpr(IN32){
            f32x4 v0=*(const f32x4*)((const float*)in + ib + (long)rr*ldin + c8);
            f32x4 v1=*(const f32x4*)((const float*)in + ib + (long)rr*ldin + c8+4);
            #pragma unroll
            for(int i=0;i<4;i++){ tl[c8+i][rr]=f2bf(v0[i]); tl[c8+4+i][rr]=f2bf(v1[i]); }
        } else {
            s16x8 v=*(const s16x8*)((const unsigned short*)in + ib + (long)rr*ldin + c8);
            #pragma unroll
            for(int i=0;i<8;i++) tl[c8+i][rr]=(unsigned short)v[i];
        }
    }
    __syncthreads();
    #pragma unroll
    for(int p=0;p<2;p++){
        const int rr=r0+p*32;
        s16x8 o8;
        #pragma unroll
        for(int i=0;i<8;i++) o8[i]=(short)tl[rr][c8+i];
        *(s16x8*)(out + ob + (long)rr*ldout + c8)=o8;
    }
}

// ---------------------------------------------------------------------------
template<bool GATHER, bool OBF16>
__global__ __launch_bounds__(256) void ln_k(const float* __restrict__ in,
    const float* __restrict__ w, const float* __restrict__ b,
    void* __restrict__ out, const int* __restrict__ tok)
{
    const int row = blockIdx.x, t = threadIdx.x;
    const float* src;
    if constexpr (GATHER) src = in + (long)tok[row]*1024;
    else                  src = in + (long)row*1024;
    const int c = t*4;
    f32x4 xv = *(const f32x4*)(src + c);
    float s  = xv[0]+xv[1]+xv[2]+xv[3];
    float qq = xv[0]*xv[0]+xv[1]*xv[1]+xv[2]*xv[2]+xv[3]*xv[3];
    #pragma unroll
    for(int m=32;m;m>>=1){ s += __shfl_xor(s,m); qq += __shfl_xor(qq,m); }
    __shared__ float rs_[4], rq_[4];
    if((t&63)==0){ rs_[t>>6]=s; rq_[t>>6]=qq; }
    __syncthreads();
    s  = rs_[0]+rs_[1]+rs_[2]+rs_[3];
    qq = rq_[0]+rq_[1]+rq_[2]+rq_[3];
    const float mu = s*(1.f/1024.f);
    const float rstd = rsqrtf(qq*(1.f/1024.f)-mu*mu + 1e-5f);
    f32x4 wv = *(const f32x4*)(w+c), bv = *(const f32x4*)(b+c);
    if constexpr (OBF16){
        s16x4 ov;
        #pragma unroll
        for(int i=0;i<4;i++) ov[i]=(short)f2bf((xv[i]-mu)*rstd*wv[i]+bv[i]);
        *(s16x4*)((unsigned short*)out + (long)row*1024 + c) = ov;
    } else {
        f32x4 ov;
        #pragma unroll
        for(int i=0;i<4;i++) ov[i]=(xv[i]-mu)*rstd*wv[i]+bv[i];
        *(f32x4*)((float*)out + (long)row*1024 + c) = ov;
    }
}

// ---------------------------------------------------------------------------
// Slow fallback GEMM — tier-C logits only.
// ---------------------------------------------------------------------------
template<int BM,int BN,int WN,bool BIAS>
__global__ __launch_bounds__(256) void gemm_k(
    const unsigned short* __restrict__ A,
    const float* __restrict__ Bp,
    const float* __restrict__ bias,
    float* __restrict__ Cp,
    int K,int lda,int ldb,int ldc)
{
    constexpr int BK=64, PAD=24, LDS_=BK+PAD;
    constexpr int WM = 4/WN;
    constexpr int WTM = BM/WM, WTN = BN/WN;
    constexpr int FM = WTM/16, FN = WTN/16;
    __shared__ unsigned short As[BM*LDS_];
    __shared__ unsigned short Bs[BN*LDS_];

    const int t = threadIdx.x;
    const int w = t>>6, lane = t&63;
    const int wr = w / WN, wc = w % WN;
    const int lr = lane & 15, lg = lane >> 4;

    const long row0 = (long)blockIdx.y*BM;
    const long col0 = (long)blockIdx.x*BN;

    f32x4 acc[FM][FN];
    #pragma unroll
    for(int i=0;i<FM;i++)
        #pragma unroll
        for(int j=0;j<FN;j++) acc[i][j] = f32x4{0.f,0.f,0.f,0.f};

    const int NT = K/BK;
    for(int kt=0; kt<NT; ++kt){
        const int kb = kt*BK;
        {
            constexpr int PASS = BM*BK/(256*4);
            #pragma unroll
            for(int p=0;p<PASS;p++){
                int idx = (p*256+t)*4;
                int r = idx/BK, c = idx%BK;
                *(s16x4*)&As[r*LDS_+c] = *(const s16x4*)(A + (row0+r)*lda + kb + c);
            }
        }
        {
            constexpr int TPB = 256/BN;
            constexpr int KC  = BK/TPB;
            const int n = t % BN, k0 = (t/BN)*KC;
            #pragma unroll
            for(int j0=0;j0<KC;j0+=8){
                s16x8 pk;
                #pragma unroll
                for(int i=0;i<8;i++){
                    const long gk = (long)kb + k0 + j0 + i;
                    pk[i] = (short)f2bf(Bp[gk*ldb + col0 + n]);
                }
                *(s16x8*)&Bs[n*LDS_ + k0 + j0] = pk;
            }
        }
        __syncthreads();
        const unsigned short* Ar = &As[(wr*WTM + lr)*LDS_ + lg*8];
        const unsigned short* Br = &Bs[(wc*WTN + lr)*LDS_ + lg*8];
        #pragma unroll
        for(int kk=0;kk<BK/32;kk++){
            s16x8 af[FM], bfv[FN];
            #pragma unroll
            for(int i=0;i<FM;i++) af[i]  = *(const s16x8*)(Ar + i*16*LDS_ + kk*32);
            #pragma unroll
            for(int j=0;j<FN;j++) bfv[j] = *(const s16x8*)(Br + j*16*LDS_ + kk*32);
            #pragma unroll
            for(int i=0;i<FM;i++)
                #pragma unroll
                for(int j=0;j<FN;j++)
                    acc[i][j] = __builtin_amdgcn_mfma_f32_16x16x32_bf16(af[i],bfv[j],acc[i][j],0,0,0);
        }
        __syncthreads();
    }
    #pragma unroll
    for(int i=0;i<FM;i++){
        #pragma unroll
        for(int j=0;j<FN;j++){
            #pragma unroll
            for(int r=0;r<4;r++){
                long grow = row0 + wr*WTM + i*16 + lg*4 + r;
                long gcol = col0 + wc*WTN + j*16 + lr;
                float vv = acc[i][j][r];
                if constexpr (BIAS) vv += bias[gcol];
                Cp[grow*ldc + gcol] = vv;
            }
        }
    }
}

// ---------------------------------------------------------------------------
extern "C" void kernel_launch(void* const* d_in, const int* in_sizes, int n_in,
                              void* d_out, int out_size, void* d_ws, size_t ws_size,
                              hipStream_t stream)
{
    const int*   tokens  = (const int*)  d_in[0];
    const float* tok_emb = (const float*)d_in[1];
    const float* ln_e_w  = (const float*)d_in[2];
    const float* ln_e_b  = (const float*)d_in[3];
    const float* ln1_w   = (const float*)d_in[4];
    const float* ln1_b   = (const float*)d_in[5];
    const float* wq      = (const float*)d_in[6];
    const float* bq      = (const float*)d_in[7];
    const float* wk      = (const float*)d_in[8];
    const float* bk      = (const float*)d_in[9];
    const float* wv      = (const float*)d_in[10];
    const float* bv      = (const float*)d_in[11];
    const float* wo      = (const float*)d_in[12];
    const float* bo      = (const float*)d_in[13];
    const float* ln2_w   = (const float*)d_in[14];
    const float* ln2_b   = (const float*)d_in[15];
    const float* w1      = (const float*)d_in[16];
    const float* b1      = (const float*)d_in[17];
    const float* w2      = (const float*)d_in[18];
    const float* b2      = (const float*)d_in[19];
    const float* lnf_w   = (const float*)d_in[20];
    const float* lnf_b   = (const float*)d_in[21];
    const float* w_out   = (const float*)d_in[22];
    const float* b_out   = (const float*)d_in[23];

    const int D=1024;
    const long DD  = (long)D*D;
    const long WQKV_L = 3145728L;

    unsigned short *wqkvT,*woT,*w1T,*w2T,*woutT=nullptr;
    float *x,*bqkv;
    unsigned short *h,*qkv,*vt,*o,*ff;
    bool fastTier;
    if (ws_size >= 301989888ull){
        char* p=(char*)d_ws;
        wqkvT=(unsigned short*)(p);
        woT  =(unsigned short*)(p+25165824);
        w1T  =(unsigned short*)(p+33554432);
        w2T  =(unsigned short*)(p+100663296);
        woutT=(unsigned short*)(p+134217728);
        x    =(float*)(p+201326592);
        h    =(unsigned short*)(p+218103808);
        qkv  =(unsigned short*)(p+226492416);
        vt   =(unsigned short*)(p+251658240);
        o    =(unsigned short*)(p+260046848);
        ff   =(unsigned short*)(p+268435456);
        bqkv =(float*)((char*)d_out + 134217728);
        fastTier=true;
    } else {
        char* p=(char*)d_out;
        qkv  =(unsigned short*)(p);
        bqkv =(float*)(p+25165824);
        wqkvT=(unsigned short*)(p+268435456);
        woT  =(unsigned short*)(p+293601280);
        w1T  =(unsigned short*)(p+301989888);
        w2T  =(unsigned short*)(p+369098752);
        x    =(float*)(p+402653184);
        vt   =(unsigned short*)(p+444596224);
        o    =(unsigned short*)(p+452984832);
        ff   =(unsigned short*)(p+461373440);
        h    =(unsigned short*)d_ws;
        fastTier=false;
    }

    const dim3 blk(256,1,1), blk8(512,1,1);

    tr_k<true,false><<<dim3(16,16,4), blk,0,stream>>>(wq, wqkvT,         1024,1024, DD,0, WQKV_L,0, 1);
    tr_k<true,false><<<dim3(16,16,4), blk,0,stream>>>(wk, wqkvT+1048576, 1024,1024, DD,0, WQKV_L,0, 1);
    tr_k<true,false><<<dim3(16,16,4), blk,0,stream>>>(wv, wqkvT+2097152, 1024,1024, DD,0, WQKV_L,0, 1);
    tr_k<true,false><<<dim3(16,16,4), blk,0,stream>>>(wo, woT, 1024,1024, DD,0, DD,0, 1);
    if (fastTier){
        tr_k<true,true><<<dim3(16,128,4),blk,0,stream>>>(w1, w1T, 8192,1024, 8388608L,0, 8388608L,0, 1);
        tr_k<true,false><<<dim3(16,500,1),blk,0,stream>>>(w_out, woutT, 32000,1024, 0,0, 0,0, 1);
    } else {
        tr_k<true,false><<<dim3(16,128,4),blk,0,stream>>>(w1, w1T, 8192,1024, 8388608L,0, 8388608L,0, 1);
    }
    tr_k<true,false><<<dim3(64,16,4), blk,0,stream>>>(w2, w2T, 1024,4096, 4194304L,0, 4194304L,0, 1);
    cat3_k<<<48,blk,0,stream>>>(bq, bk, bv, bqkv);

    ln_k<true,false><<<4096,blk,0,stream>>>(tok_emb, ln_e_w, ln_e_b, x, tokens);

    const dim3 g_d(8,32,1);

    for(int l=0;l<4;l++){
        ln_k<false,true><<<4096,blk,0,stream>>>(x, ln1_w+l*D, ln1_b+l*D, h, nullptr);
        // fused QKV via 128^2 2-phase (768 wgs = 3 full CU rounds)
        gemm_bt<128,128,2,true,false,true,false,false,false><<<dim3(24,32,1),blk,0,stream>>>(
            h, wqkvT+l*WQKV_L, nullptr, bqkv+l*3072, nullptr, qkv,
            1024, 1024,1024,3072, 0,0,0,0,0,0, 1);
        tr_k<false,false><<<dim3(32,1,32),blk,0,stream>>>(qkv+2048, vt, 3072,2048,
            2048L*3072,64, 2097152L,131072L, 16);
        flash_k<<<dim3(16,32,1),blk,0,stream>>>(qkv, vt, o);
        gemm_bt<128,128,2,true,true,false,false,false,false><<<g_d,blk,0,stream>>>(
            o, woT+l*DD, nullptr, bo+l*D, x, x, 1024, 1024,1024,1024, 0,0,0,0,0,0, 1);
        ln_k<false,true><<<4096,blk,0,stream>>>(x, ln2_w+l*D, ln2_b+l*D, h, nullptr);
        if (fastTier){
            gemm8_k<true,true,true><<<dim3(16,32,1),blk8,0,stream>>>(
                h, w1T+l*8388608L, b1+(long)l*8192, ff, 1024, 1024,1024,4096);
        } else {
            gemm_bt<128,64,1,true,false,true,false,false,true><<<dim3(64,32,1),blk,0,stream>>>(
                h, w1T+l*8388608L, w1T+l*8388608L+4194304L, b1+(long)l*8192, nullptr, ff,
                1024, 1024,1024,4096, 0,0,0,0,0,0, 1);
        }
        gemm_bt<128,128,2,true,true,false,false,false,false><<<g_d,blk,0,stream>>>(
            ff, w2T+l*4194304L, nullptr, b2+l*D, x, x, 4096, 4096,4096,1024, 0,0,0,0,0,0, 1);
    }

    ln_k<false,true><<<4096,blk,0,stream>>>(x, lnf_w, lnf_b, h, nullptr);

    if (fastTier){
        // persistent logits: 256 blocks, each 1 row-panel x ~8 col-panels
        gemm8p_k<<<dim3(256,1,1),blk8,0,stream>>>(
            h, woutT, b_out, (float*)d_out, 1024, 1024,1024,32000);
    } else {
        gemm_k<128,128,2,true><<<dim3(250,32,1),blk,0,stream>>>(
            h, w_out, b_out, (float*)d_out, 1024, 1024,32000,32000);
    }
}

// Round 9
// 1944.507 us; speedup vs baseline: 1.1153x; 1.1153x over previous
//
#include <hip/hip_runtime.h>

typedef __attribute__((ext_vector_type(8))) short s16x8;
typedef __attribute__((ext_vector_type(4))) short s16x4;
typedef __attribute__((ext_vector_type(4))) float f32x4;

__device__ __forceinline__ unsigned short f2bf(float f){
    union{float f;unsigned u;}v; v.f=f;
    unsigned u=v.u;
    unsigned r=(u+0x7fffu+((u>>16)&1u))>>16;
    return (unsigned short)r;
}
__device__ __forceinline__ float bf2f(unsigned short s){
    union{unsigned u;float f;}v; v.u=((unsigned)s)<<16; return v.f;
}
__device__ __forceinline__ unsigned pk2t(float a, float b){
    return (__float_as_uint(a)>>16) | (__float_as_uint(b) & 0xffff0000u);
}
__device__ __forceinline__ unsigned pk2r(float a, float b){
    return (unsigned)f2bf(a) | ((unsigned)f2bf(b)<<16);
}
__device__ __forceinline__ f32x4 fmax4(f32x4 a, f32x4 b){
    f32x4 r; r[0]=fmaxf(a[0],b[0]); r[1]=fmaxf(a[1],b[1]);
    r[2]=fmaxf(a[2],b[2]); r[3]=fmaxf(a[3],b[3]); return r;
}

__device__ __forceinline__ void gl16(const void* g, void* l){
    __builtin_amdgcn_global_load_lds(
        (const __attribute__((address_space(1))) void*)g,
        (__attribute__((address_space(3))) void*)l, 16, 0, 0);
}

#define ATT_SCALE 0.125f

// ===========================================================================
// Flash attention (unchanged from R7).
// ===========================================================================
__global__ __launch_bounds__(256) void flash_k(
    const unsigned short* __restrict__ qkv,
    const unsigned short* __restrict__ vt,
    unsigned short* __restrict__ o)
{
    __shared__ __align__(16) unsigned short Pl[4][2048];
    const int t=threadIdx.x, w=t>>6, lane=t&63;
    const int lr=lane&15, lg=lane>>4;
    const int zb=blockIdx.y>>4, zh=blockIdx.y&15;
    const long sr0 = (long)zb*2048 + blockIdx.x*128 + w*32;
    const unsigned short* qb    = qkv + sr0*3072 + zh*64;
    const unsigned short* kbase = qkv + ((long)zb*2048)*3072 + 1024 + zh*64;
    const unsigned short* vtb   = vt + (long)zb*2097152 + (long)zh*131072;

    s16x8 qf[2][2];
    #pragma unroll
    for(int qg=0;qg<2;qg++)
        #pragma unroll
        for(int kc=0;kc<2;kc++)
            qf[qg][kc] = *(const s16x8*)(qb + (qg*16+lr)*3072 + kc*32 + lg*8);

    float m0=-1e30f, m1=-1e30f, l0=0.f, l1=0.f;
    f32x4 oa[2][4];
    #pragma unroll
    for(int qg=0;qg<2;qg++)
        #pragma unroll
        for(int dt=0;dt<4;dt++) oa[qg][dt]=f32x4{0.f,0.f,0.f,0.f};

    char* Pw = (char*)&Pl[w][0];
    const int swz = (lr&7)<<4;

    for(int kv0=0; kv0<2048; kv0+=64){
        f32x4 s[2][4];
        __builtin_amdgcn_s_setprio(1);
        #pragma unroll
        for(int kb=0;kb<4;kb++){
            const unsigned short* kr = kbase + (long)(kv0+kb*16+lr)*3072;
            s16x8 a0 = *(const s16x8*)(kr + lg*8);
            s16x8 a1 = *(const s16x8*)(kr + 32 + lg*8);
            #pragma unroll
            for(int qg=0;qg<2;qg++){
                f32x4 z4{0.f,0.f,0.f,0.f};
                z4 = __builtin_amdgcn_mfma_f32_16x16x32_bf16(a0, qf[qg][0], z4,0,0,0);
                s[qg][kb] = __builtin_amdgcn_mfma_f32_16x16x32_bf16(a1, qf[qg][1], z4,0,0,0);
            }
        }
        __builtin_amdgcn_s_setprio(0);
        s16x8 vreg[4][2];
        #pragma unroll
        for(int dt=0;dt<4;dt++){
            const unsigned short* vr = vtb + (dt*16+lr)*2048 + kv0;
            vreg[dt][0] = *(const s16x8*)(vr + lg*8);
            vreg[dt][1] = *(const s16x8*)(vr + 32 + lg*8);
        }
        #pragma unroll
        for(int qg=0;qg<2;qg++){
            float& m = qg? m1:m0;
            float& l = qg? l1:l0;
            f32x4 mx4 = fmax4(fmax4(s[qg][0],s[qg][1]),fmax4(s[qg][2],s[qg][3]));
            float bm = fmaxf(fmaxf(mx4[0],mx4[1]),fmaxf(mx4[2],mx4[3]));
            bm = fmaxf(bm, __shfl_xor(bm,16));
            bm = fmaxf(bm, __shfl_xor(bm,32));
            const float mn = fmaxf(m, bm);
            const float sc = __expf((m-mn)*ATT_SCALE);
            m = mn;
            float rs=0.f;
            #pragma unroll
            for(int kb=0;kb<4;kb++){
                f32x4 p;
                #pragma unroll
                for(int r=0;r<4;r++){ p[r]=__expf((s[qg][kb][r]-mn)*ATT_SCALE); rs+=p[r]; }
                s[qg][kb]=p;
            }
            rs += __shfl_xor(rs,16);
            rs += __shfl_xor(rs,32);
            l = l*sc + rs;
            #pragma unroll
            for(int dt=0;dt<4;dt++) oa[qg][dt] = oa[qg][dt]*sc;
            #pragma unroll
            for(int kb=0;kb<4;kb++){
                uint2 pw;
                pw.x = pk2t(s[qg][kb][0], s[qg][kb][1]);
                pw.y = pk2t(s[qg][kb][2], s[qg][kb][3]);
                *(uint2*)(Pw + (qg*16+lr)*128 + ((kb*32+lg*8)^swz)) = pw;
            }
        }
        asm volatile("s_waitcnt lgkmcnt(0)" ::: "memory");
        s16x8 pb0[2], pb1[2];
        #pragma unroll
        for(int qg=0;qg<2;qg++){
            pb0[qg] = *(const s16x8*)(Pw + (qg*16+lr)*128 + ((     lg*16)^swz));
            pb1[qg] = *(const s16x8*)(Pw + (qg*16+lr)*128 + ((64 + lg*16)^swz));
        }
        __builtin_amdgcn_s_setprio(1);
        #pragma unroll
        for(int dt=0;dt<4;dt++){
            #pragma unroll
            for(int qg=0;qg<2;qg++){
                oa[qg][dt] = __builtin_amdgcn_mfma_f32_16x16x32_bf16(vreg[dt][0], pb0[qg], oa[qg][dt],0,0,0);
                oa[qg][dt] = __builtin_amdgcn_mfma_f32_16x16x32_bf16(vreg[dt][1], pb1[qg], oa[qg][dt],0,0,0);
            }
        }
        __builtin_amdgcn_s_setprio(0);
    }
    #pragma unroll
    for(int qg=0;qg<2;qg++){
        const float inv = 1.f/(qg? l1:l0);
        #pragma unroll
        for(int dt=0;dt<4;dt++){
            uint2 st;
            st.x = pk2r(oa[qg][dt][0]*inv, oa[qg][dt][1]*inv);
            st.y = pk2r(oa[qg][dt][2]*inv, oa[qg][dt][3]*inv);
            *(uint2*)(o + (sr0+qg*16+lr)*1024 + zh*64 + dt*16 + lg*4) = st;
        }
    }
}

// ===========================================================================
// 4-barrier 256x256 GEMM. Epilogues: bf16 / f32-LDS-staged / GEGLU / QKV+V^T.
// QKVV: col-tiles >=2048 are the V projection -> written transposed to vtp
//       as vt[b][h][d][s] (s16x4 over 4 consecutive s); q,k written normally.
// ===========================================================================
template<bool OBF16,bool BIAS,bool GEGLU,bool QKVV>
__global__ __launch_bounds__(512,2) void gemm8_k(
    const unsigned short* __restrict__ A,
    const unsigned short* __restrict__ B,
    const float* __restrict__ bias,
    void* __restrict__ Cp,
    unsigned short* __restrict__ vtp,
    int K,int lda,int ldb,int ldc)
{
    __shared__ __align__(16) char lds[131072];
    const int t=threadIdx.x, w=t>>6, lane=t&63;
    const int wr=w>>2, wc=w&3;
    const int lr=lane&15, lg=lane>>4;

    const int nwg = gridDim.x*gridDim.y;
    const int id  = blockIdx.y*gridDim.x + blockIdx.x;
    const int nid = (id&7)*(nwg>>3) + (id>>3);
    const long row0 = (long)(nid % gridDim.x)*256;
    const long col0 = (long)(nid / gridDim.x)*256;

    const int NT = K>>6;

    const int csw0 = (lg*16) ^ ((lr&7)<<4);
    const int aRow = (wr*64+lr)*128;
    const int bRow = (wc*32+lr)*128;

    const int sro = t>>3;
    const int sce = (((t&7) ^ ((t>>3)&7))<<3);

#define STAGE(gp, ld_, lb) do{ \
    const unsigned short* _g=(gp); char* _l=(lb); \
    gl16(_g + (long)sro*(ld_) + sce, _l + t*16); \
    gl16(_g + (long)(sro+64)*(ld_) + sce, _l + 8192 + t*16); }while(0)

#define LDA8(m,kk) (*(const s16x8*)(Ab_ + aRow + ((m)&3)*2048 + ((m)>>2)*16384 + ((kk)? (csw0^64):csw0)))
#define LDB8(n,kk) (*(const s16x8*)(Bb_ + bRow + ((n)&1)*2048 + ((n)>>1)*16384 + ((kk)? (csw0^64):csw0)))

    f32x4 acc[8][4];
    #pragma unroll
    for(int m=0;m<8;m++)
        #pragma unroll
        for(int n=0;n<4;n++) acc[m][n]=f32x4{0.f,0.f,0.f,0.f};

    STAGE(A + row0*lda,        lda, lds);
    STAGE(B + col0*ldb,        ldb, lds+65536);
    STAGE(A + (row0+128)*lda,  lda, lds+16384);
    STAGE(B + (col0+128)*ldb,  ldb, lds+65536+16384);
    STAGE(A + row0*lda + 64,   lda, lds+32768);
    STAGE(B + col0*ldb + 64,   ldb, lds+65536+32768);
    asm volatile("s_waitcnt vmcnt(4)" ::: "memory");
    __builtin_amdgcn_s_barrier();

    for(int tt=0; tt<NT; ++tt){
        char* Ab_ = lds + ((tt&1)<<15);
        char* Bb_ = lds + 65536 + ((tt&1)<<15);
        char* An  = lds + (((tt+1)&1)<<15);
        char* Bn  = lds + 65536 + (((tt+1)&1)<<15);
        const int k1=(tt+1)<<6, k2=(tt+2)<<6;
        s16x8 a[4][2], b[4][2];

        #pragma unroll
        for(int m=0;m<4;m++){ a[m][0]=LDA8(m,0); a[m][1]=LDA8(m,1); }
        #pragma unroll
        for(int n=0;n<4;n++){ b[n][0]=LDB8(n,0); b[n][1]=LDB8(n,1); }
        if(tt+1<NT){
            STAGE(A + (row0+128)*lda + k1, lda, An+16384);
            STAGE(B + (col0+128)*ldb + k1, ldb, Bn+16384);
        }
        __builtin_amdgcn_s_barrier();
        __builtin_amdgcn_s_setprio(1);
        #pragma unroll
        for(int kk=0;kk<2;kk++)
            #pragma unroll
            for(int m=0;m<4;m++)
                #pragma unroll
                for(int n=0;n<4;n++)
                    acc[m][n]=__builtin_amdgcn_mfma_f32_16x16x32_bf16(a[m][kk],b[n][kk],acc[m][n],0,0,0);
        __builtin_amdgcn_s_setprio(0);
        __builtin_amdgcn_s_barrier();

        #pragma unroll
        for(int m=0;m<4;m++){ a[m][0]=LDA8(m+4,0); a[m][1]=LDA8(m+4,1); }
        if(tt+2<NT){
            STAGE(A + row0*lda + k2, lda, Ab_);
            STAGE(B + col0*ldb + k2, ldb, Bb_);
        }
        __builtin_amdgcn_s_barrier();
        __builtin_amdgcn_s_setprio(1);
        #pragma unroll
        for(int kk=0;kk<2;kk++)
            #pragma unroll
            for(int m=0;m<4;m++)
                #pragma unroll
                for(int n=0;n<4;n++)
                    acc[m+4][n]=__builtin_amdgcn_mfma_f32_16x16x32_bf16(a[m][kk],b[n][kk],acc[m+4][n],0,0,0);
        __builtin_amdgcn_s_setprio(0);
        if(tt+2<NT) asm volatile("s_waitcnt vmcnt(4)" ::: "memory");
        else        asm volatile("s_waitcnt vmcnt(0)" ::: "memory");
        __builtin_amdgcn_s_barrier();
    }

    if constexpr(GEGLU){
        const long hc0 = col0>>1;
        #pragma unroll
        for(int m=0;m<8;m++){
            #pragma unroll
            for(int n=0;n<2;n++){
                #pragma unroll
                for(int rr=0;rr<4;rr++){
                    const long grow = row0 + wr*64 + (m&3)*16 + (m>>2)*128 + lg*4 + rr;
                    const long g    = hc0 + wc*32 + n*16 + lr;
                    float gg = acc[m][n][rr]   + bias[g];
                    float vl = acc[m][n+2][rr] + bias[4096+g];
                    float ge = 0.5f*gg*(1.f+erff(gg*0.70710678118654752f));
                    ((unsigned short*)Cp)[grow*(long)ldc + g] = f2bf(ge*vl);
                }
            }
        }
    } else if constexpr(QKVV){
        #pragma unroll
        for(int m=0;m<8;m++){
            #pragma unroll
            for(int n=0;n<4;n++){
                const long grow0 = row0 + wr*64 + (m&3)*16 + (m>>2)*128 + lg*4;
                const long gcol  = col0 + wc*32 + (n&1)*16 + (n>>1)*128 + lr;
                if (gcol < 2048){   // q,k: normal row-major write (block-uniform branch)
                    #pragma unroll
                    for(int rr=0;rr<4;rr++){
                        float vv = acc[m][n][rr];
                        if constexpr(BIAS) vv += bias[gcol];
                        ((unsigned short*)Cp)[(grow0+rr)*(long)ldc+gcol]=f2bf(vv);
                    }
                } else {            // v: transposed write into vt[b][h][d][s]
                    const long d  = gcol - 2048;
                    float bb = 0.f;
                    if constexpr(BIAS) bb = bias[gcol];
                    s16x4 o4;
                    #pragma unroll
                    for(int rr=0;rr<4;rr++) o4[rr]=(short)f2bf(acc[m][n][rr]+bb);
                    *(s16x4*)(vtp + (grow0>>11)*2097152 + (d>>6)*131072
                              + (d&63)*2048 + (grow0&2047)) = o4;
                }
            }
        }
    } else if constexpr(!OBF16){
        // swizzled LDS-staged coalesced f32 epilogue, nontemporal stores
        float* L = (float*)lds;
        const int lc4 = (t&63)<<2;
        f32x4 bv{0.f,0.f,0.f,0.f};
        if constexpr(BIAS) bv = *(const f32x4*)(bias + col0 + lc4);
        #pragma unroll
        for(int ch=0; ch<2; ch++){
            __builtin_amdgcn_s_barrier();
            #pragma unroll
            for(int mm=0;mm<4;mm++){
                #pragma unroll
                for(int n=0;n<4;n++){
                    #pragma unroll
                    for(int rr=0;rr<4;rr++){
                        const int lrow = wr*64 + mm*16 + lg*4 + rr;
                        const int lcol = wc*32 + (n&1)*16 + (n>>1)*128 + lr;
                        const int pc = ((((lcol>>2) ^ (lrow&7))<<2) | (lcol&3));
                        L[lrow*256 + pc] = acc[ch*4+mm][n][rr];
                    }
                }
            }
            __builtin_amdgcn_s_barrier();
            #pragma unroll
            for(int p=0;p<16;p++){
                const int lrow = p*8 + (t>>6);
                const int pc4 = (((lc4>>2) ^ (lrow&7))<<2);
                f32x4 v4 = *(const f32x4*)(L + lrow*256 + pc4);
                if constexpr(BIAS){ v4[0]+=bv[0]; v4[1]+=bv[1]; v4[2]+=bv[2]; v4[3]+=bv[3]; }
                __builtin_nontemporal_store(v4,
                    (f32x4*)((float*)Cp + (row0 + ch*128 + lrow)*(long)ldc + col0 + lc4));
            }
        }
    } else {
        #pragma unroll
        for(int m=0;m<8;m++){
            #pragma unroll
            for(int n=0;n<4;n++){
                #pragma unroll
                for(int rr=0;rr<4;rr++){
                    const long grow = row0 + wr*64 + (m&3)*16 + (m>>2)*128 + lg*4 + rr;
                    const long gcol = col0 + wc*32 + (n&1)*16 + (n>>1)*128 + lr;
                    float vv = acc[m][n][rr];
                    if constexpr(BIAS) vv += bias[gcol];
                    ((unsigned short*)Cp)[grow*(long)ldc+gcol]=f2bf(vv);
                }
            }
        }
    }
#undef STAGE
#undef LDA8
#undef LDB8
}

// ---------------------------------------------------------------------------
__global__ __launch_bounds__(256) void cat3_k(const float* __restrict__ a,
    const float* __restrict__ b, const float* __restrict__ c,
    float* __restrict__ out)
{
    const int i = blockIdx.x*256+threadIdx.x;
    const int l = i/3072, cc = i%3072;
    float v = (cc<1024)? a[l*1024+cc] : (cc<2048)? b[l*1024+cc-1024] : c[l*1024+cc-2048];
    out[i]=v;
}

// ---------------------------------------------------------------------------
// Fast 2-phase GEMM (m97 structure), 128-tile family (unchanged).
// ---------------------------------------------------------------------------
template<int BM,int BN,int WN,bool BIAS,bool RES,bool OBF16,bool SCL,bool SWAP,bool GEGLU>
__global__ __launch_bounds__(256) void gemm_bt(
    const unsigned short* __restrict__ A,
    const unsigned short* __restrict__ B,
    const unsigned short* __restrict__ B2,
    const float* __restrict__ bias,
    const float* __restrict__ res,
    void* __restrict__ Cp,
    int K,int lda,int ldb,int ldc,
    long aSb,long aSh,long bSb,long bSh,long cSb,long cSh,int zH)
{
    constexpr int BK=64;
    constexpr int WM=4/WN, WTM=BM/WM, WTN=BN/WN;
    constexpr int FM=WTM/16, FN=WTN/16;
    constexpr int CA=BM/8, CB=BN/8;
    __shared__ __align__(16) unsigned short As[BM*BK];
    __shared__ __align__(16) unsigned short Bs[BN*BK*(GEGLU?2:1)];

    const int t=threadIdx.x, w=t>>6, lane=t&63;
    const int wr=w/WN, wc=w%WN;
    const int lr=lane&15, lg=lane>>4;
    const int z=blockIdx.z, zb=z/zH, zh=z%zH;
    const long row0 = SWAP ? (long)blockIdx.x*BM : (long)blockIdx.y*BM;
    const long col0 = SWAP ? (long)blockIdx.y*BN : (long)blockIdx.x*BN;

    const unsigned short* Ab = A + zb*aSb + zh*aSh;
    const unsigned short* Bb = B + zb*bSb + zh*bSh;

    const int lr8 = lane>>3;
    const int lc8 = (lane&7)<<3;

    f32x4 acc[FM][FN];
    f32x4 acc2[GEGLU?FM:1][GEGLU?FN:1];
    #pragma unroll
    for(int i=0;i<FM;i++)
        #pragma unroll
        for(int j=0;j<FN;j++){
            acc[i][j]=f32x4{0.f,0.f,0.f,0.f};
            if constexpr(GEGLU) acc2[i][j]=f32x4{0.f,0.f,0.f,0.f};
        }

    const int NT=K/BK;
    for(int kt=0;kt<NT;kt++){
        const int kb=kt*BK;
        #pragma unroll
        for(int cc=0;cc<CA/4;cc++){
            const int c=cc*4+w;
            gl16(Ab + (row0 + c*8 + lr8)*(long)lda + kb + lc8, (char*)As + c*1024);
        }
        #pragma unroll
        for(int cc=0;cc<CB/4;cc++){
            const int c=cc*4+w;
            gl16(Bb + (col0 + c*8 + lr8)*(long)ldb + kb + lc8, (char*)Bs + c*1024);
        }
        if constexpr(GEGLU){
            #pragma unroll
            for(int cc=0;cc<CB/4;cc++){
                const int c=cc*4+w;
                gl16(B2 + (col0 + c*8 + lr8)*(long)ldb + kb + lc8,
                     (char*)Bs + (CB + c)*1024);
            }
        }
        __syncthreads();
        const unsigned short* Arp = As + (wr*WTM+lr)*BK + lg*8;
        const unsigned short* Brp = Bs + (wc*WTN+lr)*BK + lg*8;
        #pragma unroll
        for(int kk=0;kk<2;kk++){
            s16x8 af[FM], bfv[FN], bf2[GEGLU?FN:1];
            #pragma unroll
            for(int i=0;i<FM;i++) af[i] = *(const s16x8*)(Arp + i*16*BK + kk*32);
            #pragma unroll
            for(int j=0;j<FN;j++) bfv[j]= *(const s16x8*)(Brp + j*16*BK + kk*32);
            if constexpr(GEGLU){
                #pragma unroll
                for(int j=0;j<FN;j++) bf2[j]=*(const s16x8*)(Brp + BN*BK + j*16*BK + kk*32);
            }
            #pragma unroll
            for(int i=0;i<FM;i++)
                #pragma unroll
                for(int j=0;j<FN;j++){
                    acc[i][j]=__builtin_amdgcn_mfma_f32_16x16x32_bf16(af[i],bfv[j],acc[i][j],0,0,0);
                    if constexpr(GEGLU)
                        acc2[i][j]=__builtin_amdgcn_mfma_f32_16x16x32_bf16(af[i],bf2[j],acc2[i][j],0,0,0);
                }
        }
        __syncthreads();
    }
    #pragma unroll
    for(int i=0;i<FM;i++){
        #pragma unroll
        for(int j=0;j<FN;j++){
            #pragma unroll
            for(int r=0;r<4;r++){
                const long grow = row0 + wr*WTM + i*16 + lg*4 + r;
                const long gcol = col0 + wc*WTN + j*16 + lr;
                if constexpr(GEGLU){
                    float g  = acc[i][j][r]  + bias[gcol];
                    float vl = acc2[i][j][r] + bias[gcol+4096];
                    float ge = 0.5f*g*(1.f+erff(g*0.70710678118654752f));
                    ((unsigned short*)Cp)[grow*ldc+gcol] = f2bf(ge*vl);
                } else {
                    float vv=acc[i][j][r];
                    if constexpr(SCL)  vv*=ATT_SCALE;
                    if constexpr(BIAS) vv+=bias[gcol];
                    if constexpr(RES)  vv+=res[grow*ldc+gcol];
                    const long cidx = zb*cSb + zh*cSh + grow*ldc + gcol;
                    if constexpr(OBF16) ((unsigned short*)Cp)[cidx]=f2bf(vv);
                    else                ((float*)Cp)[cidx]=vv;
                }
            }
        }
    }
}

// ---------------------------------------------------------------------------
// Tiled 64x64 transpose, 16B vectorized stores.
// ---------------------------------------------------------------------------
template<bool IN32, bool REMAP>
__global__ __launch_bounds__(256) void tr_k(const void* __restrict__ in,
    unsigned short* __restrict__ out, int ldin, int ldout,
    long inZb, long inZh, long outZb, long outZh, int zH)
{
    __shared__ unsigned short tl[64][66];
    const int t=threadIdx.x;
    const int z=blockIdx.z, zb=z/zH, zh=z%zH;
    const long ib=(long)blockIdx.x*64*ldin + (long)blockIdx.y*64 + zb*inZb + zh*inZh;
    long orow = (long)blockIdx.y*64;
    if constexpr(REMAP){
        orow = (orow < 4096) ? ((orow>>7)*256 + (orow&127))
                             : (((orow-4096)>>7)*256 + 128 + ((orow-4096)&127));
    }
    const long ob=orow*ldout + (long)blockIdx.x*64 + zb*outZb + zh*outZh;
    const int r0=t>>3, c8=(t&7)*8;
    #pragma unroll
    for(int p=0;p<2;p++){
        const int rr=r0+p*32;
        if constexpr(IN32){
            f32x4 v0=*(const f32x4*)((const float*)in + ib + (long)rr*ldin + c8);
            f32x4 v1=*(const f32x4*)((const float*)in + ib + (long)rr*ldin + c8+4);
            #pragma unroll
            for(int i=0;i<4;i++){ tl[c8+i][rr]=f2bf(v0[i]); tl[c8+4+i][rr]=f2bf(v1[i]); }
        } else {
            s16x8 v=*(const s16x8*)((const unsigned short*)in + ib + (long)rr*ldin + c8);
            #pragma unroll
            for(int i=0;i<8;i++) tl[c8+i][rr]=(unsigned short)v[i];
        }
    }
    __syncthreads();
    #pragma unroll
    for(int p=0;p<2;p++){
        const int rr=r0+p*32;
        s16x8 o8;
        #pragma unroll
        for(int i=0;i<8;i++) o8[i]=(short)tl[rr][c8+i];
        *(s16x8*)(out + ob + (long)rr*ldout + c8)=o8;
    }
}

// ---------------------------------------------------------------------------
template<bool GATHER, bool OBF16>
__global__ __launch_bounds__(256) void ln_k(const float* __restrict__ in,
    const float* __restrict__ w, const float* __restrict__ b,
    void* __restrict__ out, const int* __restrict__ tok)
{
    const int row = blockIdx.x, t = threadIdx.x;
    const float* src;
    if constexpr (GATHER) src = in + (long)tok[row]*1024;
    else                  src = in + (long)row*1024;
    const int c = t*4;
    f32x4 xv = *(const f32x4*)(src + c);
    float s  = xv[0]+xv[1]+xv[2]+xv[3];
    float qq = xv[0]*xv[0]+xv[1]*xv[1]+xv[2]*xv[2]+xv[3]*xv[3];
    #pragma unroll
    for(int m=32;m;m>>=1){ s += __shfl_xor(s,m); qq += __shfl_xor(qq,m); }
    __shared__ float rs_[4], rq_[4];
    if((t&63)==0){ rs_[t>>6]=s; rq_[t>>6]=qq; }
    __syncthreads();
    s  = rs_[0]+rs_[1]+rs_[2]+rs_[3];
    qq = rq_[0]+rq_[1]+rq_[2]+rq_[3];
    const float mu = s*(1.f/1024.f);
    const float rstd = rsqrtf(qq*(1.f/1024.f)-mu*mu + 1e-5f);
    f32x4 wv = *(const f32x4*)(w+c), bv = *(const f32x4*)(b+c);
    if constexpr (OBF16){
        s16x4 ov;
        #pragma unroll
        for(int i=0;i<4;i++) ov[i]=(short)f2bf((xv[i]-mu)*rstd*wv[i]+bv[i]);
        *(s16x4*)((unsigned short*)out + (long)row*1024 + c) = ov;
    } else {
        f32x4 ov;
        #pragma unroll
        for(int i=0;i<4;i++) ov[i]=(xv[i]-mu)*rstd*wv[i]+bv[i];
        *(f32x4*)((float*)out + (long)row*1024 + c) = ov;
    }
}

// ---------------------------------------------------------------------------
// Slow fallback GEMM — tier-C logits only.
// ---------------------------------------------------------------------------
template<int BM,int BN,int WN,bool BIAS>
__global__ __launch_bounds__(256) void gemm_k(
    const unsigned short* __restrict__ A,
    const float* __restrict__ Bp,
    const float* __restrict__ bias,
    float* __restrict__ Cp,
    int K,int lda,int ldb,int ldc)
{
    constexpr int BK=64, PAD=24, LDS_=BK+PAD;
    constexpr int WM = 4/WN;
    constexpr int WTM = BM/WM, WTN = BN/WN;
    constexpr int FM = WTM/16, FN = WTN/16;
    __shared__ unsigned short As[BM*LDS_];
    __shared__ unsigned short Bs[BN*LDS_];

    const int t = threadIdx.x;
    const int w = t>>6, lane = t&63;
    const int wr = w / WN, wc = w % WN;
    const int lr = lane & 15, lg = lane >> 4;

    const long row0 = (long)blockIdx.y*BM;
    const long col0 = (long)blockIdx.x*BN;

    f32x4 acc[FM][FN];
    #pragma unroll
    for(int i=0;i<FM;i++)
        #pragma unroll
        for(int j=0;j<FN;j++) acc[i][j] = f32x4{0.f,0.f,0.f,0.f};

    const int NT = K/BK;
    for(int kt=0; kt<NT; ++kt){
        const int kb = kt*BK;
        {
            constexpr int PASS = BM*BK/(256*4);
            #pragma unroll
            for(int p=0;p<PASS;p++){
                int idx = (p*256+t)*4;
                int r = idx/BK, c = idx%BK;
                *(s16x4*)&As[r*LDS_+c] = *(const s16x4*)(A + (row0+r)*lda + kb + c);
            }
        }
        {
            constexpr int TPB = 256/BN;
            constexpr int KC  = BK/TPB;
            const int n = t % BN, k0 = (t/BN)*KC;
            #pragma unroll
            for(int j0=0;j0<KC;j0+=8){
                s16x8 pk;
                #pragma unroll
                for(int i=0;i<8;i++){
                    const long gk = (long)kb + k0 + j0 + i;
                    pk[i] = (short)f2bf(Bp[gk*ldb + col0 + n]);
                }
                *(s16x8*)&Bs[n*LDS_ + k0 + j0] = pk;
            }
        }
        __syncthreads();
        const unsigned short* Ar = &As[(wr*WTM + lr)*LDS_ + lg*8];
        const unsigned short* Br = &Bs[(wc*WTN + lr)*LDS_ + lg*8];
        #pragma unroll
        for(int kk=0;kk<BK/32;kk++){
            s16x8 af[FM], bfv[FN];
            #pragma unroll
            for(int i=0;i<FM;i++) af[i]  = *(const s16x8*)(Ar + i*16*LDS_ + kk*32);
            #pragma unroll
            for(int j=0;j<FN;j++) bfv[j] = *(const s16x8*)(Br + j*16*LDS_ + kk*32);
            #pragma unroll
            for(int i=0;i<FM;i++)
                #pragma unroll
                for(int j=0;j<FN;j++)
                    acc[i][j] = __builtin_amdgcn_mfma_f32_16x16x32_bf16(af[i],bfv[j],acc[i][j],0,0,0);
        }
        __syncthreads();
    }
    #pragma unroll
    for(int i=0;i<FM;i++){
        #pragma unroll
        for(int j=0;j<FN;j++){
            #pragma unroll
            for(int r=0;r<4;r++){
                long grow = row0 + wr*WTM + i*16 + lg*4 + r;
                long gcol = col0 + wc*WTN + j*16 + lr;
                float vv = acc[i][j][r];
                if constexpr (BIAS) vv += bias[gcol];
                Cp[grow*ldc + gcol] = vv;
            }
        }
    }
}

// ---------------------------------------------------------------------------
extern "C" void kernel_launch(void* const* d_in, const int* in_sizes, int n_in,
                              void* d_out, int out_size, void* d_ws, size_t ws_size,
                              hipStream_t stream)
{
    const int*   tokens  = (const int*)  d_in[0];
    const float* tok_emb = (const float*)d_in[1];
    const float* ln_e_w  = (const float*)d_in[2];
    const float* ln_e_b  = (const float*)d_in[3];
    const float* ln1_w   = (const float*)d_in[4];
    const float* ln1_b   = (const float*)d_in[5];
    const float* wq      = (const float*)d_in[6];
    const float* bq      = (const float*)d_in[7];
    const float* wk      = (const float*)d_in[8];
    const float* bk      = (const float*)d_in[9];
    const float* wv      = (const float*)d_in[10];
    const float* bv      = (const float*)d_in[11];
    const float* wo      = (const float*)d_in[12];
    const float* bo      = (const float*)d_in[13];
    const float* ln2_w   = (const float*)d_in[14];
    const float* ln2_b   = (const float*)d_in[15];
    const float* w1      = (const float*)d_in[16];
    const float* b1      = (const float*)d_in[17];
    const float* w2      = (const float*)d_in[18];
    const float* b2      = (const float*)d_in[19];
    const float* lnf_w   = (const float*)d_in[20];
    const float* lnf_b   = (const float*)d_in[21];
    const float* w_out   = (const float*)d_in[22];
    const float* b_out   = (const float*)d_in[23];

    const int D=1024;
    const long DD  = (long)D*D;
    const long WQKV_L = 3145728L;

    unsigned short *wqkvT,*woT,*w1T,*w2T,*woutT=nullptr;
    float *x,*bqkv;
    unsigned short *h,*qkv,*vt,*o,*ff;
    bool fastTier;
    if (ws_size >= 301989888ull){
        char* p=(char*)d_ws;
        wqkvT=(unsigned short*)(p);
        woT  =(unsigned short*)(p+25165824);
        w1T  =(unsigned short*)(p+33554432);
        w2T  =(unsigned short*)(p+100663296);
        woutT=(unsigned short*)(p+134217728);
        x    =(float*)(p+201326592);
        h    =(unsigned short*)(p+218103808);
        qkv  =(unsigned short*)(p+226492416);
        vt   =(unsigned short*)(p+251658240);
        o    =(unsigned short*)(p+260046848);
        ff   =(unsigned short*)(p+268435456);
        bqkv =(float*)((char*)d_out + 134217728);
        fastTier=true;
    } else {
        char* p=(char*)d_out;
        qkv  =(unsigned short*)(p);
        bqkv =(float*)(p+25165824);
        wqkvT=(unsigned short*)(p+268435456);
        woT  =(unsigned short*)(p+293601280);
        w1T  =(unsigned short*)(p+301989888);
        w2T  =(unsigned short*)(p+369098752);
        x    =(float*)(p+402653184);
        vt   =(unsigned short*)(p+444596224);
        o    =(unsigned short*)(p+452984832);
        ff   =(unsigned short*)(p+461373440);
        h    =(unsigned short*)d_ws;
        fastTier=false;
    }

    const dim3 blk(256,1,1), blk8(512,1,1);

    tr_k<true,false><<<dim3(16,16,4), blk,0,stream>>>(wq, wqkvT,         1024,1024, DD,0, WQKV_L,0, 1);
    tr_k<true,false><<<dim3(16,16,4), blk,0,stream>>>(wk, wqkvT+1048576, 1024,1024, DD,0, WQKV_L,0, 1);
    tr_k<true,false><<<dim3(16,16,4), blk,0,stream>>>(wv, wqkvT+2097152, 1024,1024, DD,0, WQKV_L,0, 1);
    tr_k<true,false><<<dim3(16,16,4), blk,0,stream>>>(wo, woT, 1024,1024, DD,0, DD,0, 1);
    if (fastTier){
        tr_k<true,true><<<dim3(16,128,4),blk,0,stream>>>(w1, w1T, 8192,1024, 8388608L,0, 8388608L,0, 1);
        tr_k<true,false><<<dim3(16,500,1),blk,0,stream>>>(w_out, woutT, 32000,1024, 0,0, 0,0, 1);
    } else {
        tr_k<true,false><<<dim3(16,128,4),blk,0,stream>>>(w1, w1T, 8192,1024, 8388608L,0, 8388608L,0, 1);
    }
    tr_k<true,false><<<dim3(64,16,4), blk,0,stream>>>(w2, w2T, 1024,4096, 4194304L,0, 4194304L,0, 1);
    cat3_k<<<48,blk,0,stream>>>(bq, bk, bv, bqkv);

    ln_k<true,false><<<4096,blk,0,stream>>>(tok_emb, ln_e_w, ln_e_b, x, tokens);

    const dim3 g_d(8,32,1);

    for(int l=0;l<4;l++){
        ln_k<false,true><<<4096,blk,0,stream>>>(x, ln1_w+l*D, ln1_b+l*D, h, nullptr);
        // fused QKV (4096 x 3072) with V written transposed into vt
        gemm8_k<true,true,false,true><<<dim3(16,12,1),blk8,0,stream>>>(
            h, wqkvT+l*WQKV_L, bqkv+l*3072, qkv, vt, 1024, 1024,1024,3072);
        // flash attention -> o
        flash_k<<<dim3(16,32,1),blk,0,stream>>>(qkv, vt, o);
        // x += o @ wo + bo
        gemm_bt<128,128,2,true,true,false,false,false,false><<<g_d,blk,0,stream>>>(
            o, woT+l*DD, nullptr, bo+l*D, x, x, 1024, 1024,1024,1024, 0,0,0,0,0,0, 1);
        // FFN
        ln_k<false,true><<<4096,blk,0,stream>>>(x, ln2_w+l*D, ln2_b+l*D, h, nullptr);
        if (fastTier){
            gemm8_k<true,true,true,false><<<dim3(16,32,1),blk8,0,stream>>>(
                h, w1T+l*8388608L, b1+(long)l*8192, ff, nullptr, 1024, 1024,1024,4096);
        } else {
            gemm_bt<128,64,1,true,false,true,false,false,true><<<dim3(64,32,1),blk,0,stream>>>(
                h, w1T+l*8388608L, w1T+l*8388608L+4194304L, b1+(long)l*8192, nullptr, ff,
                1024, 1024,1024,4096, 0,0,0,0,0,0, 1);
        }
        gemm_bt<128,128,2,true,true,false,false,false,false><<<g_d,blk,0,stream>>>(
            ff, w2T+l*4194304L, nullptr, b2+l*D, x, x, 4096, 4096,4096,1024, 0,0,0,0,0,0, 1);
    }

    ln_k<false,true><<<4096,blk,0,stream>>>(x, lnf_w, lnf_b, h, nullptr);

    if (fastTier){
        gemm8_k<false,true,false,false><<<dim3(16,125,1),blk8,0,stream>>>(
            h, woutT, b_out, (float*)d_out, nullptr, 1024, 1024,1024,32000);
    } else {
        gemm_k<128,128,2,true><<<dim3(250,32,1),blk,0,stream>>>(
            h, w_out, b_out, (float*)d_out, 1024, 1024,32000,32000);
    }
}